// Round 3
// baseline (1521.518 us; speedup 1.0000x reference)
//
#include <hip/hip_runtime.h>
#include <hip/hip_bf16.h>
#include <cmath>
#include <cstring>

#define B_SZ   512
#define SLEN   1000
#define DD     16
#define HID    256
#define WIN    64
#define PAIRS  120
#define LSIG   136
#define LMAX   4

struct PreArgs  { short snapk[SLEN - 1]; };                       // ~2KB kernarg, ok
struct ChunkArgs{ int nc; unsigned char st[WIN], ln[WIN], fl[WIN]; };

// ---------------------------------------------------------------- init: dtsqrt
__global__ void init_kernel(float* __restrict__ dtsqrt) {
  int t = blockIdx.x * blockDim.x + threadIdx.x;
  if (t < SLEN - 1) {
    const double s999 = 1.0 / (double)(SLEN - 1);
    double a = (t + 1 == SLEN - 1) ? 1.0 : (double)(t + 1) * s999;
    double b = (double)t * s999;
    dtsqrt[t] = sqrtf((float)(a - b));
  }
}

// ------------------------------------------------- preprocess: z -> logsig
// one block per batch row; threads 0..119 own a (i,j) pair; threads 0..15 also
// track X[d] for lvl1 snapshots. Sequential t-scan.
// Window rule (matches reference): levy[k] = 0.5*(C[t_idx] - C[50*floor(t_idx/50)])
// -> reset Acc when POSITION t+1 hits a multiple of 50, BEFORE the snapshot at
//    that position (so a snapshot exactly at a window boundary reads 0).
__global__ __launch_bounds__(128) void preproc_kernel(
    const float* __restrict__ z, const float* __restrict__ dtsqrt,
    float* __restrict__ logsig, PreArgs A)
{
  const int b = blockIdx.x, tid = threadIdx.x;
  __shared__ float zn[2][DD];

  int pi = 0, pj = 0;
  if (tid < PAIRS) {            // triu_indices(16,1) row-major
    int rem = tid, i = 0;
    while (rem >= DD - 1 - i) { rem -= DD - 1 - i; ++i; }
    pi = i; pj = i + 1 + rem;
  }
  // slot 0 of seq is zeros
  for (int idx = tid; idx < LSIG; idx += 128)
    logsig[((size_t)b * WIN + 0) * LSIG + idx] = 0.f;

  float Xa = 0.f, Xb = 0.f, Acc = 0.f, Xd = 0.f;
  const float* zrow = z + (size_t)b * SLEN * DD;
  if (tid < DD) zn[0][tid] = zrow[DD + tid] * dtsqrt[0];
  __syncthreads();

  int next50 = 50;
  for (int t = 0; t < SLEN - 1; ++t) {
    const int cur = t & 1;
    if (tid < DD && t + 2 < SLEN)
      zn[cur ^ 1][tid] = zrow[(size_t)(t + 2) * DD + tid] * dtsqrt[t + 1];
    const float zi = zn[cur][pi], zj = zn[cur][pj];
    Acc = fmaf(Xa, zj, Acc);
    Acc = fmaf(-Xb, zi, Acc);          // Acc += Xp[i]*dX[j] - Xp[j]*dX[i]
    Xa += zi; Xb += zj;                // X_{t+1}
    if (tid < DD) Xd += zn[cur][tid];
    if (t + 1 == next50) { Acc = 0.f; next50 += 50; }  // window boundary at pos t+1
    const int m = A.snapk[t];          // nonzero if t+1 == t_idx[m-1]
    if (m) {
      float* dst = logsig + ((size_t)b * WIN + m) * LSIG;
      if (tid < DD)    dst[tid]       = Xd;          // lvl1 = X[t_idx]
      if (tid < PAIRS) dst[DD + tid]  = 0.5f * Acc;  // levy
    }
    __syncthreads();
  }
}

// ------------------------------------------------------------- RNN layers
template <int L, int TANH>
__device__ __forceinline__ void layer_mm(
    int j, const float4* __restrict__ wr, float bias,
    const float (&in)[2][LMAX][HID], float (&outb)[2][LMAX][HID])
{
  float acc[2][L];
#pragma unroll
  for (int r = 0; r < 2; ++r)
#pragma unroll
    for (int l = 0; l < L; ++l) acc[r][l] = bias;
#pragma unroll 4
  for (int q = 0; q < HID / 4; ++q) {
    const float4 w = wr[q];
#pragma unroll
    for (int r = 0; r < 2; ++r)
#pragma unroll
      for (int l = 0; l < L; ++l) {
        const float4 x = *(const float4*)&in[r][l][4 * q];
        acc[r][l] = fmaf(w.x, x.x, acc[r][l]);
        acc[r][l] = fmaf(w.y, x.y, acc[r][l]);
        acc[r][l] = fmaf(w.z, x.z, acc[r][l]);
        acc[r][l] = fmaf(w.w, x.w, acc[r][l]);
      }
  }
#pragma unroll
  for (int r = 0; r < 2; ++r)
#pragma unroll
    for (int l = 0; l < L; ++l)
      outb[r][l][j] = TANH ? tanhf(acc[r][l]) : fmaxf(acc[r][l], 0.f);
}

template <int L>
__device__ __forceinline__ void chunk_body(
    int j, int bid, int kc, int fl,
    const float* __restrict__ logsig,
    const float4* __restrict__ w1r, const float4* __restrict__ w2r,
    const float4* __restrict__ w3r, const float4* __restrict__ wlr,
    float bb1, float bb2, float bb3,
    float (&S)[2][HID], float (&ls)[2][LMAX][LSIG],
    float (&bufA)[2][LMAX][HID], float (&bufB)[2][LMAX][HID],
    float* __restrict__ out)
{
  // stage this chunk's logsig slices
  for (int idx = j; idx < L * 2 * LSIG; idx += HID) {
    const int l  = idx / (2 * LSIG);
    const int rem = idx - l * 2 * LSIG;
    const int r  = rem / LSIG;
    const int cc = rem - r * LSIG;
    ls[r][l][cc] = logsig[((size_t)(2 * bid + r) * WIN + (kc + l)) * LSIG + cc];
  }
  // layer-1 state part: shared by every step in the chunk
  float base0 = bb1, base1 = bb1;
  {
    const float4* s0 = (const float4*)S[0];
    const float4* s1 = (const float4*)S[1];
#pragma unroll 8
    for (int q = 0; q < HID / 4; ++q) {
      const float4 w = w1r[q];
      const float4 x0 = s0[q], x1 = s1[q];
      base0 = fmaf(w.x, x0.x, base0); base0 = fmaf(w.y, x0.y, base0);
      base0 = fmaf(w.z, x0.z, base0); base0 = fmaf(w.w, x0.w, base0);
      base1 = fmaf(w.x, x1.x, base1); base1 = fmaf(w.y, x1.y, base1);
      base1 = fmaf(w.z, x1.z, base1); base1 = fmaf(w.w, x1.w, base1);
    }
  }
  __syncthreads();   // ls visible
  // layer-1 logsig part
  {
    float acc[2][L];
#pragma unroll
    for (int r = 0; r < 2; ++r)
#pragma unroll
      for (int l = 0; l < L; ++l) acc[r][l] = (r == 0) ? base0 : base1;
#pragma unroll 2
    for (int q = 0; q < LSIG / 4; ++q) {
      const float4 w = w1r[HID / 4 + q];
#pragma unroll
      for (int r = 0; r < 2; ++r)
#pragma unroll
        for (int l = 0; l < L; ++l) {
          const float4 x = *(const float4*)&ls[r][l][4 * q];
          acc[r][l] = fmaf(w.x, x.x, acc[r][l]);
          acc[r][l] = fmaf(w.y, x.y, acc[r][l]);
          acc[r][l] = fmaf(w.z, x.z, acc[r][l]);
          acc[r][l] = fmaf(w.w, x.w, acc[r][l]);
        }
    }
#pragma unroll
    for (int r = 0; r < 2; ++r)
#pragma unroll
      for (int l = 0; l < L; ++l) bufA[r][l][j] = fmaxf(acc[r][l], 0.f);
  }
  __syncthreads();
  layer_mm<L, 0>(j, w2r, bb2, bufA, bufB);
  __syncthreads();
  layer_mm<L, 1>(j, w3r, bb3, bufB, bufA);   // bufA now holds h (tanh)
  __syncthreads();
  // y = h @ W_lin.T  -> fp32 out
  {
    float acc[2][L];
#pragma unroll
    for (int r = 0; r < 2; ++r)
#pragma unroll
      for (int l = 0; l < L; ++l) acc[r][l] = 0.f;
#pragma unroll 4
    for (int q = 0; q < HID / 4; ++q) {
      const float4 w = wlr[q];
#pragma unroll
      for (int r = 0; r < 2; ++r)
#pragma unroll
        for (int l = 0; l < L; ++l) {
          const float4 x = *(const float4*)&bufA[r][l][4 * q];
          acc[r][l] = fmaf(w.x, x.x, acc[r][l]);
          acc[r][l] = fmaf(w.y, x.y, acc[r][l]);
          acc[r][l] = fmaf(w.z, x.z, acc[r][l]);
          acc[r][l] = fmaf(w.w, x.w, acc[r][l]);
        }
    }
#pragma unroll
    for (int r = 0; r < 2; ++r)
#pragma unroll
      for (int l = 0; l < L; ++l)
        out[((size_t)(2 * bid + r) * WIN + (kc + l)) * HID + j] = acc[r][l];
  }
  if (fl) { S[0][j] = bufA[0][L - 1][j]; S[1][j] = bufA[1][L - 1][j]; }
  __syncthreads();   // S ready for next chunk; buffers reusable
}

__global__ __launch_bounds__(HID) void rnn_kernel(
    const float* __restrict__ logsig,
    const float* __restrict__ W1, const float* __restrict__ b1,
    const float* __restrict__ W2, const float* __restrict__ b2,
    const float* __restrict__ W3, const float* __restrict__ b3,
    const float* __restrict__ Wl,
    float* __restrict__ out, ChunkArgs A)
{
  __shared__ float S[2][HID];
  __shared__ float ls[2][LMAX][LSIG];
  __shared__ float bufA[2][LMAX][HID];
  __shared__ float bufB[2][LMAX][HID];
  const int j = threadIdx.x, bid = blockIdx.x;
  S[0][j] = 0.f; S[1][j] = 0.f;
  const float4* w1r = (const float4*)(W1 + (size_t)j * (HID + LSIG));
  const float4* w2r = (const float4*)(W2 + (size_t)j * HID);
  const float4* w3r = (const float4*)(W3 + (size_t)j * HID);
  const float4* wlr = (const float4*)(Wl + (size_t)j * HID);
  const float bb1 = b1[j], bb2 = b2[j], bb3 = b3[j];
  __syncthreads();
  for (int c = 0; c < A.nc; ++c) {
    const int kc = A.st[c], L = A.ln[c], fl = A.fl[c];
    switch (L) {
      case 4: chunk_body<4>(j, bid, kc, fl, logsig, w1r, w2r, w3r, wlr, bb1, bb2, bb3, S, ls, bufA, bufB, out); break;
      case 3: chunk_body<3>(j, bid, kc, fl, logsig, w1r, w2r, w3r, wlr, bb1, bb2, bb3, S, ls, bufA, bufB, out); break;
      case 2: chunk_body<2>(j, bid, kc, fl, logsig, w1r, w2r, w3r, wlr, bb1, bb2, bb3, S, ls, bufA, bufB, out); break;
      default: chunk_body<1>(j, bid, kc, fl, logsig, w1r, w2r, w3r, wlr, bb1, bb2, bb3, S, ls, bufA, bufB, out); break;
    }
  }
}

// ------------------------------------------------------------- host schedule
static void build_host_sched(PreArgs& P, ChunkArgs& C) {
  double tb[SLEN], tt[WIN], tu[20];
  const double s999 = 1.0 / (double)(SLEN - 1);
  const double s63  = 1.0 / (double)(WIN - 1);
  for (int i = 0; i < SLEN; ++i) tb[i] = (double)i * s999;
  tb[SLEN - 1] = 1.0;
  for (int k = 0; k < WIN; ++k) tt[k] = (double)k * s63;
  tt[WIN - 1] = 1.0;
  for (int j = 0; j < 20; ++j) tu[j] = tb[50 * j];

  int t_idx[WIN - 1], u_for_t[WIN - 1];
  for (int k = 1; k < WIN; ++k) {
    int ii = 0;
    for (int q = 0; q < SLEN; ++q) if (tb[q] <= tt[k]) ii = q;
    t_idx[k - 1] = ii;
    int jj = 0;
    for (int q = 0; q < 20; ++q) if (tu[q] <= tt[k]) jj = q;
    u_for_t[k - 1] = jj;
  }
  for (int t = 0; t < SLEN - 1; ++t) P.snapk[t] = 0;
  for (int m = 1; m < WIN; ++m) P.snapk[t_idx[m - 1] - 1] = (short)m;

  double qt[32]; int nq = 0, last = -1;
  for (int m = 0; m < WIN - 1; ++m) {
    const int iu = u_for_t[m];
    if (iu != last) { qt[nq++] = tu[iu]; last = iu; }
  }
  qt[nq++] = tt[WIN - 1];
  int upd[WIN]; int qh = 0;
  for (int i = 0; i < WIN; ++i) {
    upd[i] = 0;
    if (qh < nq && tt[i] >= qt[qh]) { qh++; upd[i] = 1; }
  }
  C.nc = 0; int cs = 0;
  for (int k = 0; k < WIN; ++k) {
    if (upd[k]) {
      int s = cs;
      while (k - s + 1 > LMAX) {
        C.st[C.nc] = (unsigned char)s; C.ln[C.nc] = LMAX; C.fl[C.nc] = 0; C.nc++; s += LMAX;
      }
      C.st[C.nc] = (unsigned char)s; C.ln[C.nc] = (unsigned char)(k - s + 1); C.fl[C.nc] = 1; C.nc++;
      cs = k + 1;
    }
  }
  while (cs < WIN) {
    int L = WIN - cs; if (L > LMAX) L = LMAX;
    C.st[C.nc] = (unsigned char)cs; C.ln[C.nc] = (unsigned char)L; C.fl[C.nc] = 0; C.nc++;
    cs += L;
  }
}

extern "C" void kernel_launch(void* const* d_in, const int* in_sizes, int n_in,
                              void* d_out, int out_size, void* d_ws, size_t ws_size,
                              hipStream_t stream) {
  const float* z  = (const float*)d_in[0];
  const float* W1 = (const float*)d_in[1];
  const float* b1 = (const float*)d_in[2];
  const float* W2 = (const float*)d_in[3];
  const float* b2 = (const float*)d_in[4];
  const float* W3 = (const float*)d_in[5];
  const float* b3 = (const float*)d_in[6];
  const float* Wl = (const float*)d_in[7];

  float* dtsqrt = (float*)d_ws;                       // 999 floats
  float* logsig = (float*)((char*)d_ws + 4096);       // 512*64*136 floats

  PreArgs P; ChunkArgs C;
  build_host_sched(P, C);

  init_kernel<<<4, 256, 0, stream>>>(dtsqrt);
  preproc_kernel<<<B_SZ, 128, 0, stream>>>(z, dtsqrt, logsig, P);
  rnn_kernel<<<B_SZ / 2, HID, 0, stream>>>(logsig, W1, b1, W2, b2, W3, b3, Wl,
                                           (float*)d_out, C);
}

// Round 4
// 712.946 us; speedup vs baseline: 2.1341x; 2.1341x over previous
//
#include <hip/hip_runtime.h>
#include <hip/hip_bf16.h>
#include <cmath>
#include <cstring>

#define B_SZ   512
#define SLEN   1000
#define DD     16
#define HID    256
#define WIN    64
#define PAIRS  120
#define LSIG   136
#define NWIN   20
#define MAXST  21      // state slots per batch row (0..20)
#define K1P    416     // layer-1 K padded to x32

using short8 = __attribute__((ext_vector_type(8))) short;
using f32x4  = __attribute__((ext_vector_type(4))) float;

struct SchedArgs { short snapk[SLEN - 1]; };                    // ~2KB kernarg (worked before)
struct CombArgs  { unsigned char winofm[WIN]; unsigned char zl[WIN]; };
struct ChainArgs { int nsteps; unsigned char kU[32]; };
struct FuseArgs  { unsigned char sidx[WIN]; };

__device__ __forceinline__ unsigned short f2bf(float x) {
  __hip_bfloat16 h = __float2bfloat16(x);
  return *(unsigned short*)&h;
}

// ---------------------------------------------------------------- dtsqrt
__global__ void init_kernel(float* __restrict__ dtsqrt) {
  int t = blockIdx.x * blockDim.x + threadIdx.x;
  if (t < SLEN - 1) {
    const double s999 = 1.0 / (double)(SLEN - 1);
    double a = (t + 1 == SLEN - 1) ? 1.0 : (double)(t + 1) * s999;
    double b = (double)t * s999;
    dtsqrt[t] = sqrtf((float)(a - b));
  }
}

// ---------------------------------------------------------------- weights -> bf16
__global__ void wbf_kernel(const float* __restrict__ W1, const float* __restrict__ W2,
                           const float* __restrict__ W3, const float* __restrict__ Wl,
                           unsigned short* __restrict__ W1b, unsigned short* __restrict__ W2b,
                           unsigned short* __restrict__ W3b, unsigned short* __restrict__ Wlb) {
  int idx = blockIdx.x * 256 + threadIdx.x;
  if (idx < HID * K1P) {
    int r = idx / K1P, c = idx - r * K1P;
    float v = (c < HID + LSIG) ? W1[(size_t)r * (HID + LSIG) + c] : 0.f;  // zero-pad cols 392..415
    W1b[idx] = f2bf(v);
  } else {
    int j = idx - HID * K1P;
    if (j < 3 * HID * HID) {
      int which = j / (HID * HID), o = j - which * (HID * HID);
      const float* src = which == 0 ? W2 : which == 1 ? W3 : Wl;
      unsigned short* dst = which == 0 ? W2b : which == 1 ? W3b : Wlb;
      dst[o] = f2bf(src[o]);
    }
  }
}

// ---------------------------------------------------------------- per-window scan
// Window w covers increments q in [50w, 50w+50) (49 for w=19). Computes, relative
// to window start s=50w:  Y_p (partial cumsum) and LL_p = sum Y_i dX_j - Y_j dX_i
// at each snapshot position p=q+1, plus the window total dX. K2 adds the
// cross-window correction: C_p - C_s = LL_p + Xs_i Y_pj - Xs_j Y_pi.
__global__ __launch_bounds__(128) void win_kernel(
    const float* __restrict__ z, const float* __restrict__ dtsqrt,
    float* __restrict__ logsig, float* __restrict__ dxwin, SchedArgs A)
{
  const int w = blockIdx.x, b = blockIdx.y, tid = threadIdx.x;
  __shared__ float zs[50][16];
  const int ns = (w == NWIN - 1) ? 49 : 50;
  const float* src = z + ((size_t)b * SLEN + 50 * w + 1) * DD;
  for (int c = tid; c < ns * 4; c += 128) {           // pre-scaled increments into LDS
    float4 v = ((const float4*)src)[c];
    float s = dtsqrt[50 * w + (c >> 2)];
    v.x *= s; v.y *= s; v.z *= s; v.w *= s;
    ((float4*)&zs[0][0])[c] = v;
  }
  int pi = 0, pj = 0;
  if (tid < PAIRS) { int rem = tid, i = 0; while (rem >= DD - 1 - i) { rem -= DD - 1 - i; ++i; } pi = i; pj = i + 1 + rem; }
  __syncthreads();
  float Yi = 0.f, Yj = 0.f, LL = 0.f, Yd = 0.f;
  const int base_t = 50 * w;
  for (int u = 0; u < ns; ++u) {
    const float di = zs[u][pi], dj = zs[u][pj];
    LL = fmaf(Yi, dj, LL); LL = fmaf(-Yj, di, LL);    // uses Y BEFORE this increment
    Yi += di; Yj += dj;
    if (tid < DD) Yd += zs[u][tid];
    const int m = A.snapk[base_t + u];                // nonzero if pos u+1+50w is t_idx[m-1]
    if (m) {
      float* dst = logsig + ((size_t)b * WIN + m) * LSIG;
      if (tid < DD)    dst[tid]      = Yd;            // Y at snapshot (lvl1 pre-correction)
      if (tid < PAIRS) dst[DD + tid] = LL;            // local levy (un-halved, uncorrected)
    }
  }
  if (tid < DD) dxwin[((size_t)b * NWIN + w) * DD + tid] = Yd;
}

// ---------------------------------------------------------------- combine windows
__global__ __launch_bounds__(128) void comb_kernel(
    float* __restrict__ logsig, const float* __restrict__ dxwin, CombArgs A)
{
  const int b = blockIdx.x, tid = threadIdx.x;
  __shared__ float Xs[NWIN][DD];
  __shared__ float Yt[DD];
  int pi = 0, pj = 0;
  if (tid < PAIRS) { int rem = tid, i = 0; while (rem >= DD - 1 - i) { rem -= DD - 1 - i; ++i; } pi = i; pj = i + 1 + rem; }
  if (tid < DD) {
    float acc = 0.f;
    for (int w = 0; w < NWIN; ++w) { Xs[w][tid] = acc; acc += dxwin[((size_t)b * NWIN + w) * DD + tid]; }
  }
  for (int c = tid; c < LSIG; c += 128) logsig[(size_t)b * WIN * LSIG + c] = 0.f;  // row 0 zeros
  __syncthreads();
  for (int m = 1; m < WIN; ++m) {
    float* row = logsig + ((size_t)b * WIN + m) * LSIG;
    float ll = 0.f;
    if (tid < DD) Yt[tid] = row[tid];
    if (tid < PAIRS) ll = row[DD + tid];
    __syncthreads();
    const int w = A.winofm[m];
    if (tid < PAIRS) {
      float levy = A.zl[m] ? 0.f
                 : 0.5f * (ll + Xs[w][pi] * Yt[pj] - Xs[w][pj] * Yt[pi]);
      row[DD + tid] = levy;
    }
    if (tid < DD) row[tid] = Xs[w][tid] + Yt[tid];
    __syncthreads();
  }
}

// ---------------------------------------------------------------- sequential state chain (fp32)
__global__ __launch_bounds__(256) void chain_kernel(
    const float* __restrict__ logsig,
    const float* __restrict__ W1, const float* __restrict__ b1,
    const float* __restrict__ W2, const float* __restrict__ b2,
    const float* __restrict__ W3, const float* __restrict__ b3,
    unsigned short* __restrict__ statesb, ChainArgs A)
{
  __shared__ float S[2][HID], lsb[2][LSIG], bufA[2][HID], bufB[2][HID];
  const int j = threadIdx.x, bid = blockIdx.x;
  const float4* w1r = (const float4*)(W1 + (size_t)j * (HID + LSIG));
  const float4* w2r = (const float4*)(W2 + (size_t)j * HID);
  const float4* w3r = (const float4*)(W3 + (size_t)j * HID);
  const float bb1 = b1[j], bb2 = b2[j], bb3 = b3[j];
  S[0][j] = 0.f; S[1][j] = 0.f;
  statesb[((size_t)(2 * bid + 0) * MAXST + 0) * HID + j] = 0;   // state 0 = +0.0 bf16
  statesb[((size_t)(2 * bid + 1) * MAXST + 0) * HID + j] = 0;
  __syncthreads();
  for (int m = 0; m < A.nsteps; ++m) {
    const int k = A.kU[m];
    for (int idx = j; idx < 2 * LSIG; idx += HID) {
      int r = idx >= LSIG; int c = idx - r * LSIG;
      lsb[r][c] = logsig[((size_t)(2 * bid + r) * WIN + k) * LSIG + c];
    }
    __syncthreads();
    { // L1: K = 256 (state) + 136 (logsig)
      float a0 = bb1, a1 = bb1;
      const float4* s0 = (const float4*)S[0]; const float4* s1 = (const float4*)S[1];
#pragma unroll 8
      for (int q = 0; q < HID / 4; ++q) {
        float4 wv = w1r[q]; float4 x0 = s0[q], x1 = s1[q];
        a0 = fmaf(wv.x, x0.x, a0); a0 = fmaf(wv.y, x0.y, a0); a0 = fmaf(wv.z, x0.z, a0); a0 = fmaf(wv.w, x0.w, a0);
        a1 = fmaf(wv.x, x1.x, a1); a1 = fmaf(wv.y, x1.y, a1); a1 = fmaf(wv.z, x1.z, a1); a1 = fmaf(wv.w, x1.w, a1);
      }
      const float4* l0 = (const float4*)lsb[0]; const float4* l1 = (const float4*)lsb[1];
#pragma unroll 4
      for (int q = 0; q < LSIG / 4; ++q) {
        float4 wv = w1r[HID / 4 + q]; float4 x0 = l0[q], x1 = l1[q];
        a0 = fmaf(wv.x, x0.x, a0); a0 = fmaf(wv.y, x0.y, a0); a0 = fmaf(wv.z, x0.z, a0); a0 = fmaf(wv.w, x0.w, a0);
        a1 = fmaf(wv.x, x1.x, a1); a1 = fmaf(wv.y, x1.y, a1); a1 = fmaf(wv.z, x1.z, a1); a1 = fmaf(wv.w, x1.w, a1);
      }
      bufA[0][j] = fmaxf(a0, 0.f); bufA[1][j] = fmaxf(a1, 0.f);
    }
    __syncthreads();
    { // L2
      float a0 = bb2, a1 = bb2;
      const float4* x0p = (const float4*)bufA[0]; const float4* x1p = (const float4*)bufA[1];
#pragma unroll 8
      for (int q = 0; q < HID / 4; ++q) {
        float4 wv = w2r[q]; float4 x0 = x0p[q], x1 = x1p[q];
        a0 = fmaf(wv.x, x0.x, a0); a0 = fmaf(wv.y, x0.y, a0); a0 = fmaf(wv.z, x0.z, a0); a0 = fmaf(wv.w, x0.w, a0);
        a1 = fmaf(wv.x, x1.x, a1); a1 = fmaf(wv.y, x1.y, a1); a1 = fmaf(wv.z, x1.z, a1); a1 = fmaf(wv.w, x1.w, a1);
      }
      bufB[0][j] = fmaxf(a0, 0.f); bufB[1][j] = fmaxf(a1, 0.f);
    }
    __syncthreads();
    { // L3 + tanh -> new state
      float a0 = bb3, a1 = bb3;
      const float4* x0p = (const float4*)bufB[0]; const float4* x1p = (const float4*)bufB[1];
#pragma unroll 8
      for (int q = 0; q < HID / 4; ++q) {
        float4 wv = w3r[q]; float4 x0 = x0p[q], x1 = x1p[q];
        a0 = fmaf(wv.x, x0.x, a0); a0 = fmaf(wv.y, x0.y, a0); a0 = fmaf(wv.z, x0.z, a0); a0 = fmaf(wv.w, x0.w, a0);
        a1 = fmaf(wv.x, x1.x, a1); a1 = fmaf(wv.y, x1.y, a1); a1 = fmaf(wv.z, x1.z, a1); a1 = fmaf(wv.w, x1.w, a1);
      }
      float t0 = tanhf(a0), t1 = tanhf(a1);
      S[0][j] = t0; S[1][j] = t1;
      statesb[((size_t)(2 * bid + 0) * MAXST + (m + 1)) * HID + j] = f2bf(t0);
      statesb[((size_t)(2 * bid + 1) * MAXST + (m + 1)) * HID + j] = f2bf(t1);
    }
    __syncthreads();
  }
}

// ---------------------------------------------------------------- fused batched MLP (bf16 MFMA)
// 256 blocks, 1/CU; block = 128 rows (2 batch rows x 64 steps), all 4 layers.
// act layout [128][264] bf16 (stride 264 -> 2-way-max bank aliasing = free).
// streamed tiles [128][40] (stride 40 -> 2-way).
template <int EPI>  // 0 relu->LDS, 1 tanh->LDS, 2 none->global fp32
__device__ __forceinline__ void layer_234(
    const unsigned short* __restrict__ inb, unsigned short* __restrict__ outb,
    const unsigned short* __restrict__ Wb, const float* __restrict__ bias,
    float* __restrict__ outg, int band, unsigned short* __restrict__ wtile,
    int tid, int wm, int wn, int l15, int lq)
{
  for (int nh = 0; nh < 2; ++nh) {
    f32x4 acc[4][4];
#pragma unroll
    for (int a = 0; a < 4; ++a)
#pragma unroll
      for (int t = 0; t < 4; ++t) acc[a][t] = (f32x4){0.f, 0.f, 0.f, 0.f};
    for (int kk = 0; kk < HID; kk += 32) {
#pragma unroll
      for (int i = 0; i < 2; ++i) {
        int c = tid + 256 * i; int n = c >> 2, cc = (c & 3) * 8;
        short8 wv = *(const short8*)(Wb + ((size_t)(nh * 128 + n)) * HID + kk + cc);
        *(short8*)&wtile[n * 40 + cc] = wv;
      }
      __syncthreads();
      short8 af[4], bfr[4];
#pragma unroll
      for (int a = 0; a < 4; ++a) af[a]  = *(const short8*)&inb[(wm * 64 + a * 16 + l15) * 264 + kk + lq * 8];
#pragma unroll
      for (int t = 0; t < 4; ++t) bfr[t] = *(const short8*)&wtile[(wn * 64 + t * 16 + l15) * 40 + lq * 8];
#pragma unroll
      for (int a = 0; a < 4; ++a)
#pragma unroll
        for (int t = 0; t < 4; ++t)
          acc[a][t] = __builtin_amdgcn_mfma_f32_16x16x32_bf16(af[a], bfr[t], acc[a][t], 0, 0, 0);
      __syncthreads();
    }
#pragma unroll
    for (int t = 0; t < 4; ++t) {
      int col = nh * 128 + wn * 64 + t * 16 + l15;
      float bv = (EPI < 2) ? bias[col] : 0.f;
#pragma unroll
      for (int a = 0; a < 4; ++a)
#pragma unroll
        for (int r4 = 0; r4 < 4; ++r4) {
          int row = wm * 64 + a * 16 + lq * 4 + r4;
          float v = acc[a][t][r4] + bv;
          if (EPI == 0) { outb[row * 264 + col] = f2bf(fmaxf(v, 0.f)); }
          else if (EPI == 1) { outb[row * 264 + col] = f2bf(tanhf(v)); }
          else { outg[((size_t)(band * 128 + row)) * HID + col] = v; }
        }
    }
  }
  __syncthreads();
}

__global__ __launch_bounds__(256, 1) void fused_kernel(
    const unsigned short* __restrict__ statesb, const float* __restrict__ logsig,
    const unsigned short* __restrict__ W1b, const unsigned short* __restrict__ W2b,
    const unsigned short* __restrict__ W3b, const unsigned short* __restrict__ Wlb,
    const float* __restrict__ b1, const float* __restrict__ b2, const float* __restrict__ b3,
    float* __restrict__ out, FuseArgs F)
{
  __shared__ __align__(16) unsigned short act1[128 * 264];
  __shared__ __align__(16) unsigned short act2[128 * 264];
  __shared__ __align__(16) unsigned short atile[128 * 40];
  __shared__ __align__(16) unsigned short wtile[128 * 40];
  const int tid = threadIdx.x, band = blockIdx.x;
  const int lane = tid & 63, wave = tid >> 6;
  const int wm = wave & 1, wn = wave >> 1;
  const int l15 = lane & 15, lq = lane >> 4;

  // ---- layer 1: A streamed from states(bf16) + logsig(fp32->bf16), K=416
  for (int nh = 0; nh < 2; ++nh) {
    f32x4 acc[4][4];
#pragma unroll
    for (int a = 0; a < 4; ++a)
#pragma unroll
      for (int t = 0; t < 4; ++t) acc[a][t] = (f32x4){0.f, 0.f, 0.f, 0.f};
    for (int kk = 0; kk < K1P; kk += 32) {
#pragma unroll
      for (int i = 0; i < 2; ++i) {        // stage A-tile 128x32
        int c = tid + 256 * i;
        int r = c >> 2, cc = (c & 3) * 8;
        int col = kk + cc;                 // branch uniform per kk (col block within one side)
        int bA = band * 2 + (r >> 6), ks = r & 63;
        short8 pk;
        if (col < HID) {
          pk = *(const short8*)(statesb + ((size_t)bA * MAXST + F.sidx[ks]) * HID + col);
        } else {
          const float* sp = logsig + ((size_t)bA * WIN + ks) * LSIG + (col - HID); // may read past 136: benign, W-pad=0
          float4 v0 = ((const float4*)sp)[0];
          float4 v1 = ((const float4*)sp)[1];
          pk[0] = (short)f2bf(v0.x); pk[1] = (short)f2bf(v0.y); pk[2] = (short)f2bf(v0.z); pk[3] = (short)f2bf(v0.w);
          pk[4] = (short)f2bf(v1.x); pk[5] = (short)f2bf(v1.y); pk[6] = (short)f2bf(v1.z); pk[7] = (short)f2bf(v1.w);
        }
        *(short8*)&atile[r * 40 + cc] = pk;
      }
#pragma unroll
      for (int i = 0; i < 2; ++i) {        // stage W-tile 128x32
        int c = tid + 256 * i; int n = c >> 2, cc = (c & 3) * 8;
        short8 wv = *(const short8*)(W1b + ((size_t)(nh * 128 + n)) * K1P + kk + cc);
        *(short8*)&wtile[n * 40 + cc] = wv;
      }
      __syncthreads();
      short8 af[4], bfr[4];
#pragma unroll
      for (int a = 0; a < 4; ++a) af[a]  = *(const short8*)&atile[(wm * 64 + a * 16 + l15) * 40 + lq * 8];
#pragma unroll
      for (int t = 0; t < 4; ++t) bfr[t] = *(const short8*)&wtile[(wn * 64 + t * 16 + l15) * 40 + lq * 8];
#pragma unroll
      for (int a = 0; a < 4; ++a)
#pragma unroll
        for (int t = 0; t < 4; ++t)
          acc[a][t] = __builtin_amdgcn_mfma_f32_16x16x32_bf16(af[a], bfr[t], acc[a][t], 0, 0, 0);
      __syncthreads();
    }
#pragma unroll
    for (int t = 0; t < 4; ++t) {          // epilogue: +b1, relu -> act1
      int col = nh * 128 + wn * 64 + t * 16 + l15;
      float bv = b1[col];
#pragma unroll
      for (int a = 0; a < 4; ++a)
#pragma unroll
        for (int r4 = 0; r4 < 4; ++r4) {
          int row = wm * 64 + a * 16 + lq * 4 + r4;
          act1[row * 264 + col] = f2bf(fmaxf(acc[a][t][r4] + bv, 0.f));
        }
    }
  }
  __syncthreads();

  layer_234<0>(act1, act2, W2b, b2, nullptr, band, wtile, tid, wm, wn, l15, lq);  // L2 relu
  layer_234<1>(act2, act1, W3b, b3, nullptr, band, wtile, tid, wm, wn, l15, lq);  // L3 tanh -> h
  layer_234<2>(act1, nullptr, Wlb, nullptr, out, band, wtile, tid, wm, wn, l15, lq);  // y -> out
}

// ---------------------------------------------------------------- host schedule
static void build_sched(SchedArgs& P, CombArgs& CB, ChainArgs& CH, FuseArgs& FU) {
  double tb[SLEN], tt[WIN], tu[NWIN];
  const double s999 = 1.0 / (double)(SLEN - 1);
  const double s63  = 1.0 / (double)(WIN - 1);
  for (int i = 0; i < SLEN; ++i) tb[i] = (double)i * s999;
  tb[SLEN - 1] = 1.0;
  for (int k = 0; k < WIN; ++k) tt[k] = (double)k * s63;
  tt[WIN - 1] = 1.0;
  for (int j = 0; j < NWIN; ++j) tu[j] = tb[50 * j];

  int t_idx[WIN - 1], u_for_t[WIN - 1];
  for (int k = 1; k < WIN; ++k) {
    int ii = 0;
    for (int q = 0; q < SLEN; ++q) if (tb[q] <= tt[k]) ii = q;
    t_idx[k - 1] = ii;
    int jj = 0;
    for (int q = 0; q < NWIN; ++q) if (tu[q] <= tt[k]) jj = q;
    u_for_t[k - 1] = jj;
  }
  for (int t = 0; t < SLEN - 1; ++t) P.snapk[t] = 0;
  for (int m = 1; m < WIN; ++m) P.snapk[t_idx[m - 1] - 1] = (short)m;

  for (int m = 0; m < WIN; ++m) { CB.winofm[m] = 0; CB.zl[m] = 0; }
  for (int m = 1; m < WIN; ++m) {
    int p = t_idx[m - 1];
    CB.winofm[m] = (unsigned char)((p - 1) / 50);
    CB.zl[m] = (p % 50 == 0) ? 1 : 0;
  }

  // update schedule (validated logic from passing round)
  double qt[32]; int nq = 0, last = -1;
  for (int m = 0; m < WIN - 1; ++m) {
    const int iu = u_for_t[m];
    if (iu != last) { qt[nq++] = tu[iu]; last = iu; }
  }
  qt[nq++] = tt[WIN - 1];
  int upd[WIN]; int qh = 0;
  for (int i = 0; i < WIN; ++i) {
    upd[i] = 0;
    if (qh < nq && tt[i] >= qt[qh]) { qh++; upd[i] = 1; }
  }
  int nU = 0;
  for (int k = 0; k < WIN; ++k) if (upd[k]) { if (nU < 32) CH.kU[nU] = (unsigned char)k; ++nU; }
  int cnt = 0;
  for (int k = 0; k < WIN; ++k) { FU.sidx[k] = (unsigned char)cnt; if (upd[k]) ++cnt; }
  CH.nsteps = FU.sidx[WIN - 1];   // states 1..maxsidx needed; run that many steps
}

extern "C" void kernel_launch(void* const* d_in, const int* in_sizes, int n_in,
                              void* d_out, int out_size, void* d_ws, size_t ws_size,
                              hipStream_t stream) {
  const float* z  = (const float*)d_in[0];
  const float* W1 = (const float*)d_in[1];
  const float* b1 = (const float*)d_in[2];
  const float* W2 = (const float*)d_in[3];
  const float* b2 = (const float*)d_in[4];
  const float* W3 = (const float*)d_in[5];
  const float* b3 = (const float*)d_in[6];
  const float* Wl = (const float*)d_in[7];

  char* ws = (char*)d_ws;
  float* dtsqrt          = (float*)(ws);                              //   4 KB
  float* logsig          = (float*)(ws + 4096);                       // 17.83 MB
  size_t o = 4096 + (size_t)B_SZ * WIN * LSIG * 4;
  float* dxwin           = (float*)(ws + o);  o += (size_t)B_SZ * NWIN * DD * 4;      // 0.66 MB
  unsigned short* statesb = (unsigned short*)(ws + o); o += (size_t)B_SZ * MAXST * HID * 2; // 5.5 MB
  unsigned short* W1b    = (unsigned short*)(ws + o); o += (size_t)HID * K1P * 2;
  unsigned short* W2b    = (unsigned short*)(ws + o); o += (size_t)HID * HID * 2;
  unsigned short* W3b    = (unsigned short*)(ws + o); o += (size_t)HID * HID * 2;
  unsigned short* Wlb    = (unsigned short*)(ws + o); o += (size_t)HID * HID * 2;

  SchedArgs P; CombArgs CB; ChainArgs CH; FuseArgs FU;
  build_sched(P, CB, CH, FU);

  init_kernel<<<4, 256, 0, stream>>>(dtsqrt);
  wbf_kernel<<<(HID * K1P + 3 * HID * HID + 255) / 256, 256, 0, stream>>>(
      W1, W2, W3, Wl, W1b, W2b, W3b, Wlb);
  win_kernel<<<dim3(NWIN, B_SZ), 128, 0, stream>>>(z, dtsqrt, logsig, dxwin, P);
  comb_kernel<<<B_SZ, 128, 0, stream>>>(logsig, dxwin, CB);
  chain_kernel<<<B_SZ / 2, HID, 0, stream>>>(logsig, W1, b1, W2, b2, W3, b3, statesb, CH);
  fused_kernel<<<256, 256, 0, stream>>>(statesb, logsig, W1b, W2b, W3b, Wlb,
                                        b1, b2, b3, (float*)d_out, FU);
}

// Round 6
// 342.659 us; speedup vs baseline: 4.4403x; 2.0806x over previous
//
#include <hip/hip_runtime.h>
#include <hip/hip_bf16.h>
#include <cmath>
#include <cstring>

#define B_SZ   512
#define SLEN   1000
#define DD     16
#define HID    256
#define WIN    64
#define PAIRS  120
#define LSIG   136
#define NWIN   20
#define MAXST  21      // state slots per batch row (0..20)
#define K1P    416     // layer-1 K padded to x32
#define AST    440     // LDS act row stride (shorts): 880B -> 2-way bank aliasing (free)

using short8 = __attribute__((ext_vector_type(8))) short;
using half8  = __attribute__((ext_vector_type(8))) _Float16;
using f32x4  = __attribute__((ext_vector_type(4))) float;

struct SchedArgs { short snapk[SLEN - 1]; };
struct CombArgs  { unsigned char winofm[WIN]; unsigned char zl[WIN]; };
struct ChainArgs { int nsteps; unsigned char kU[32]; };
struct FuseArgs  { unsigned char sidx[WIN]; };

__device__ __forceinline__ unsigned short f2bf(float x) {
  __hip_bfloat16 h = __float2bfloat16(x);
  return *(unsigned short*)&h;
}
__device__ __forceinline__ unsigned short f2h(float x) {
  _Float16 h = (_Float16)x;
  return __builtin_bit_cast(unsigned short, h);
}

// ---------------------------------------------------------------- weights convert
// plain bf16 (fused): W1b [256][416] (pad cols 392..=0), W2b/W3b/Wlb [256][256]
// frag fp16 (chain):  Wxf[(kk*16 + nsub)*64 + lane][8], value = W[nsub*16+(lane&15)][kk*32+(lane>>4)*8+j]
__global__ void wbf_kernel(const float* __restrict__ W1, const float* __restrict__ W2,
                           const float* __restrict__ W3, const float* __restrict__ Wl,
                           unsigned short* __restrict__ W1b, unsigned short* __restrict__ W2b,
                           unsigned short* __restrict__ W3b, unsigned short* __restrict__ Wlb,
                           unsigned short* __restrict__ W1f, unsigned short* __restrict__ W2f,
                           unsigned short* __restrict__ W3f) {
  int idx = blockIdx.x * 256 + threadIdx.x;
  if (idx < HID * K1P) {
    int r = idx / K1P, c = idx - r * K1P;
    float v = (c < HID + LSIG) ? W1[(size_t)r * (HID + LSIG) + c] : 0.f;
    W1b[idx] = f2bf(v);
    return;
  }
  int j0 = idx - HID * K1P;
  if (j0 < 3 * HID * HID) {
    int which = j0 / (HID * HID), o = j0 - which * (HID * HID);
    const float* src = which == 0 ? W2 : which == 1 ? W3 : Wl;
    unsigned short* dst = which == 0 ? W2b : which == 1 ? W3b : Wlb;
    dst[o] = f2bf(src[o]);
    return;
  }
  int f1 = j0 - 3 * HID * HID;
  if (f1 < 13 * 16 * 64 * 8) {                       // W1f (fp16)
    int f = f1;
    int j = f & 7, l15 = (f >> 3) & 15, lq = (f >> 7) & 3, nsub = (f >> 9) & 15, kk = f >> 13;
    int row = nsub * 16 + l15, col = kk * 32 + lq * 8 + j;
    float v = (col < HID + LSIG) ? W1[(size_t)row * (HID + LSIG) + col] : 0.f;
    W1f[f] = f2h(v);
    return;
  }
  int f2 = f1 - 13 * 16 * 64 * 8;
  if (f2 < 2 * 8 * 16 * 64 * 8) {                    // W2f / W3f (fp16)
    int which = f2 >> 16, f = f2 & 65535;
    int j = f & 7, l15 = (f >> 3) & 15, lq = (f >> 7) & 3, nsub = (f >> 9) & 15, kk = (f >> 13) & 7;
    int row = nsub * 16 + l15, col = kk * 32 + lq * 8 + j;
    const float* src = which == 0 ? W2 : W3;
    unsigned short* dst = which == 0 ? W2f : W3f;
    dst[f] = f2h(src[(size_t)row * HID + col]);
  }
}

// ---------------------------------------------------------------- per-window scan (dtsqrt inlined)
__global__ __launch_bounds__(128) void win_kernel(
    const float* __restrict__ z, float* __restrict__ logsig,
    float* __restrict__ dxwin, SchedArgs A)
{
  const int w = blockIdx.x, b = blockIdx.y, tid = threadIdx.x;
  __shared__ float zs[50][16];
  const int ns = (w == NWIN - 1) ? 49 : 50;
  const float* src = z + ((size_t)b * SLEN + 50 * w + 1) * DD;
  const double s999 = 1.0 / (double)(SLEN - 1);
  for (int c = tid; c < ns * 4; c += 128) {
    float4 v = ((const float4*)src)[c];
    int t = 50 * w + (c >> 2);
    double a = (t + 1 == SLEN - 1) ? 1.0 : (double)(t + 1) * s999;
    float s = sqrtf((float)(a - (double)t * s999));
    v.x *= s; v.y *= s; v.z *= s; v.w *= s;
    ((float4*)&zs[0][0])[c] = v;
  }
  int pi = 0, pj = 0;
  if (tid < PAIRS) { int rem = tid, i = 0; while (rem >= DD - 1 - i) { rem -= DD - 1 - i; ++i; } pi = i; pj = i + 1 + rem; }
  __syncthreads();
  float Yi = 0.f, Yj = 0.f, LL = 0.f, Yd = 0.f;
  const int base_t = 50 * w;
  for (int u = 0; u < ns; ++u) {
    const float di = zs[u][pi], dj = zs[u][pj];
    LL = fmaf(Yi, dj, LL); LL = fmaf(-Yj, di, LL);
    Yi += di; Yj += dj;
    if (tid < DD) Yd += zs[u][tid];
    const int m = A.snapk[base_t + u];
    if (m) {
      float* dst = logsig + ((size_t)b * WIN + m) * LSIG;
      if (tid < DD)    dst[tid]      = Yd;
      if (tid < PAIRS) dst[DD + tid] = LL;
    }
  }
  if (tid < DD) dxwin[((size_t)b * NWIN + w) * DD + tid] = Yd;
}

// ---------------------------------------------------------------- combine windows
__global__ __launch_bounds__(128) void comb_kernel(
    float* __restrict__ logsig, const float* __restrict__ dxwin, CombArgs A)
{
  const int b = blockIdx.x, tid = threadIdx.x;
  __shared__ float Xs[NWIN][DD];
  __shared__ float Yt[DD];
  int pi = 0, pj = 0;
  if (tid < PAIRS) { int rem = tid, i = 0; while (rem >= DD - 1 - i) { rem -= DD - 1 - i; ++i; } pi = i; pj = i + 1 + rem; }
  if (tid < DD) {
    float acc = 0.f;
    for (int w = 0; w < NWIN; ++w) { Xs[w][tid] = acc; acc += dxwin[((size_t)b * NWIN + w) * DD + tid]; }
  }
  for (int c = tid; c < LSIG; c += 128) logsig[(size_t)b * WIN * LSIG + c] = 0.f;
  __syncthreads();
  for (int m = 1; m < WIN; ++m) {
    float* row = logsig + ((size_t)b * WIN + m) * LSIG;
    float ll = 0.f;
    if (tid < DD) Yt[tid] = row[tid];
    if (tid < PAIRS) ll = row[DD + tid];
    __syncthreads();
    const int w = A.winofm[m];
    if (tid < PAIRS) {
      float levy = A.zl[m] ? 0.f
                 : 0.5f * (ll + Xs[w][pi] * Yt[pj] - Xs[w][pj] * Yt[pi]);
      row[DD + tid] = levy;
    }
    if (tid < DD) row[tid] = Xs[w][tid] + Yt[tid];
    __syncthreads();
  }
}

// ---------------------------------------------------------------- sequential state chain (fp16 MFMA, fp32 accum)
// 32 blocks x 512 threads (8 waves). M=16 batch rows/block. Wave w owns output
// cols [32w,32w+32). W2/W3 fp16 B-fragments in REGISTERS; W1 fp16 fragments
// streamed from L2 per step (pre-fragmented -> coalesced loads). Acts/states in
// LDS as fp16 (8x lower rounding than bf16); state EXPORTED as bf16 for fused.
__global__ __launch_bounds__(512, 2) void chain_kernel(
    const float* __restrict__ logsig,
    const unsigned short* __restrict__ W1f, const unsigned short* __restrict__ W2f,
    const unsigned short* __restrict__ W3f,
    const float* __restrict__ b1, const float* __restrict__ b2, const float* __restrict__ b3,
    unsigned short* __restrict__ statesb, ChainArgs A)
{
  __shared__ __align__(16) unsigned short A0[16][AST];  // state 0..255 | logsig 256..391 | pad0 392..415
  __shared__ __align__(16) unsigned short A1[16][AST];
  __shared__ __align__(16) unsigned short A2[16][AST];
  const int tid = threadIdx.x, g = blockIdx.x;
  const int lane = tid & 63, w = tid >> 6;
  const int l15 = lane & 15, lq = lane >> 4;

  for (int c = tid; c < 16 * AST; c += 512) ((unsigned short*)A0)[c] = 0;
  for (int c = tid; c < 16 * HID; c += 512) {           // export state 0 = zeros
    int r = c >> 8, col = c & 255;
    statesb[((size_t)(g * 16 + r) * MAXST + 0) * HID + col] = 0;
  }

  // W2/W3 fp16 fragments -> registers (compile-time indices)
  half8 w2f[2][8], w3f[2][8];
#pragma unroll
  for (int nt = 0; nt < 2; ++nt)
#pragma unroll
    for (int kk = 0; kk < 8; ++kk) {
      w2f[nt][kk] = *(const half8*)(W2f + ((size_t)(kk * 16 + (w * 2 + nt)) * 64 + lane) * 8);
      w3f[nt][kk] = *(const half8*)(W3f + ((size_t)(kk * 16 + (w * 2 + nt)) * 64 + lane) * 8);
    }
  float bias1[2], bias2[2], bias3[2];
#pragma unroll
  for (int nt = 0; nt < 2; ++nt) {
    int col = (w * 2 + nt) * 16 + l15;
    bias1[nt] = b1[col]; bias2[nt] = b2[col]; bias3[nt] = b3[col];
  }
  __syncthreads();

  for (int m = 0; m < A.nsteps; ++m) {
    const int k = A.kU[m];
    // stage logsig fp32->fp16 into A0 cols 256..391
    for (int c = tid; c < 16 * LSIG; c += 512) {
      int r = c / LSIG, cc = c - r * LSIG;
      A0[r][HID + cc] = f2h(logsig[((size_t)(g * 16 + r) * WIN + k) * LSIG + cc]);
    }
    __syncthreads();

    // ---- L1: K=416, W1 frags streamed (coalesced)
    {
      f32x4 acc[2] = {{0.f,0.f,0.f,0.f},{0.f,0.f,0.f,0.f}};
      const unsigned short* p = W1f + ((size_t)(w * 2) * 64 + lane) * 8;
#pragma unroll
      for (int kk = 0; kk < 13; ++kk) {
        half8 af = *(const half8*)&A0[l15][kk * 32 + lq * 8];
        half8 bf0 = *(const half8*)(p + (size_t)kk * 8192);
        half8 bf1 = *(const half8*)(p + (size_t)kk * 8192 + 512);
        acc[0] = __builtin_amdgcn_mfma_f32_16x16x32_f16(af, bf0, acc[0], 0, 0, 0);
        acc[1] = __builtin_amdgcn_mfma_f32_16x16x32_f16(af, bf1, acc[1], 0, 0, 0);
      }
#pragma unroll
      for (int nt = 0; nt < 2; ++nt) {
        int col = (w * 2 + nt) * 16 + l15;
#pragma unroll
        for (int r4 = 0; r4 < 4; ++r4)
          A1[lq * 4 + r4][col] = f2h(fmaxf(acc[nt][r4] + bias1[nt], 0.f));
      }
    }
    __syncthreads();

    // ---- L2: K=256, weights in registers
    {
      f32x4 acc[2] = {{0.f,0.f,0.f,0.f},{0.f,0.f,0.f,0.f}};
#pragma unroll
      for (int kk = 0; kk < 8; ++kk) {
        half8 af = *(const half8*)&A1[l15][kk * 32 + lq * 8];
        acc[0] = __builtin_amdgcn_mfma_f32_16x16x32_f16(af, w2f[0][kk], acc[0], 0, 0, 0);
        acc[1] = __builtin_amdgcn_mfma_f32_16x16x32_f16(af, w2f[1][kk], acc[1], 0, 0, 0);
      }
#pragma unroll
      for (int nt = 0; nt < 2; ++nt) {
        int col = (w * 2 + nt) * 16 + l15;
#pragma unroll
        for (int r4 = 0; r4 < 4; ++r4)
          A2[lq * 4 + r4][col] = f2h(fmaxf(acc[nt][r4] + bias2[nt], 0.f));
      }
    }
    __syncthreads();

    // ---- L3: K=256, weights in registers; tanh -> new state (A0 fp16) + export bf16
    {
      f32x4 acc[2] = {{0.f,0.f,0.f,0.f},{0.f,0.f,0.f,0.f}};
#pragma unroll
      for (int kk = 0; kk < 8; ++kk) {
        half8 af = *(const half8*)&A2[l15][kk * 32 + lq * 8];
        acc[0] = __builtin_amdgcn_mfma_f32_16x16x32_f16(af, w3f[0][kk], acc[0], 0, 0, 0);
        acc[1] = __builtin_amdgcn_mfma_f32_16x16x32_f16(af, w3f[1][kk], acc[1], 0, 0, 0);
      }
#pragma unroll
      for (int nt = 0; nt < 2; ++nt) {
        int col = (w * 2 + nt) * 16 + l15;
#pragma unroll
        for (int r4 = 0; r4 < 4; ++r4) {
          int row = lq * 4 + r4;
          float tv = tanhf(acc[nt][r4] + bias3[nt]);
          A0[row][col] = f2h(tv);
          statesb[((size_t)(g * 16 + row) * MAXST + (m + 1)) * HID + col] = f2bf(tv);
        }
      }
    }
    __syncthreads();
  }
}

// ---------------------------------------------------------------- fused batched MLP (bf16 MFMA)
template <int EPI>  // 0 relu->LDS, 1 tanh->LDS, 2 none->global fp32
__device__ __forceinline__ void layer_234(
    const unsigned short* __restrict__ inb, unsigned short* __restrict__ outb,
    const unsigned short* __restrict__ Wb, const float* __restrict__ bias,
    float* __restrict__ outg, int band, unsigned short* __restrict__ wtile,
    int tid, int wm, int wn, int l15, int lq)
{
  for (int nh = 0; nh < 2; ++nh) {
    f32x4 acc[4][4];
#pragma unroll
    for (int a = 0; a < 4; ++a)
#pragma unroll
      for (int t = 0; t < 4; ++t) acc[a][t] = (f32x4){0.f, 0.f, 0.f, 0.f};
    for (int kk = 0; kk < HID; kk += 32) {
#pragma unroll
      for (int i = 0; i < 2; ++i) {
        int c = tid + 256 * i; int n = c >> 2, cc = (c & 3) * 8;
        short8 wv = *(const short8*)(Wb + ((size_t)(nh * 128 + n)) * HID + kk + cc);
        *(short8*)&wtile[n * 40 + cc] = wv;
      }
      __syncthreads();
      short8 af[4], bfr[4];
#pragma unroll
      for (int a = 0; a < 4; ++a) af[a]  = *(const short8*)&inb[(wm * 64 + a * 16 + l15) * 264 + kk + lq * 8];
#pragma unroll
      for (int t = 0; t < 4; ++t) bfr[t] = *(const short8*)&wtile[(wn * 64 + t * 16 + l15) * 40 + lq * 8];
#pragma unroll
      for (int a = 0; a < 4; ++a)
#pragma unroll
        for (int t = 0; t < 4; ++t)
          acc[a][t] = __builtin_amdgcn_mfma_f32_16x16x32_bf16(af[a], bfr[t], acc[a][t], 0, 0, 0);
      __syncthreads();
    }
#pragma unroll
    for (int t = 0; t < 4; ++t) {
      int col = nh * 128 + wn * 64 + t * 16 + l15;
      float bv = (EPI < 2) ? bias[col] : 0.f;
#pragma unroll
      for (int a = 0; a < 4; ++a)
#pragma unroll
        for (int r4 = 0; r4 < 4; ++r4) {
          int row = wm * 64 + a * 16 + lq * 4 + r4;
          float v = acc[a][t][r4] + bv;
          if (EPI == 0) { outb[row * 264 + col] = f2bf(fmaxf(v, 0.f)); }
          else if (EPI == 1) { outb[row * 264 + col] = f2bf(tanhf(v)); }
          else { outg[((size_t)(band * 128 + row)) * HID + col] = v; }
        }
    }
  }
  __syncthreads();
}

__global__ __launch_bounds__(256, 1) void fused_kernel(
    const unsigned short* __restrict__ statesb, const float* __restrict__ logsig,
    const unsigned short* __restrict__ W1b, const unsigned short* __restrict__ W2b,
    const unsigned short* __restrict__ W3b, const unsigned short* __restrict__ Wlb,
    const float* __restrict__ b1, const float* __restrict__ b2, const float* __restrict__ b3,
    float* __restrict__ out, FuseArgs F)
{
  __shared__ __align__(16) unsigned short act1[128 * 264];
  __shared__ __align__(16) unsigned short act2[128 * 264];
  __shared__ __align__(16) unsigned short atile[128 * 40];
  __shared__ __align__(16) unsigned short wtile[128 * 40];
  const int tid = threadIdx.x, band = blockIdx.x;
  const int lane = tid & 63, wave = tid >> 6;
  const int wm = wave & 1, wn = wave >> 1;
  const int l15 = lane & 15, lq = lane >> 4;

  for (int nh = 0; nh < 2; ++nh) {
    f32x4 acc[4][4];
#pragma unroll
    for (int a = 0; a < 4; ++a)
#pragma unroll
      for (int t = 0; t < 4; ++t) acc[a][t] = (f32x4){0.f, 0.f, 0.f, 0.f};
    for (int kk = 0; kk < K1P; kk += 32) {
#pragma unroll
      for (int i = 0; i < 2; ++i) {        // stage A-tile 128x32
        int c = tid + 256 * i;
        int r = c >> 2, cc = (c & 3) * 8;
        int col = kk + cc;
        int bA = band * 2 + (r >> 6), ks = r & 63;
        short8 pk;
        if (col < HID) {
          pk = *(const short8*)(statesb + ((size_t)bA * MAXST + F.sidx[ks]) * HID + col);
        } else {
          const float* sp = logsig + ((size_t)bA * WIN + ks) * LSIG + (col - HID);
          float4 v0 = ((const float4*)sp)[0];
          float4 v1 = ((const float4*)sp)[1];
          pk[0] = (short)f2bf(v0.x); pk[1] = (short)f2bf(v0.y); pk[2] = (short)f2bf(v0.z); pk[3] = (short)f2bf(v0.w);
          pk[4] = (short)f2bf(v1.x); pk[5] = (short)f2bf(v1.y); pk[6] = (short)f2bf(v1.z); pk[7] = (short)f2bf(v1.w);
        }
        *(short8*)&atile[r * 40 + cc] = pk;
      }
#pragma unroll
      for (int i = 0; i < 2; ++i) {        // stage W-tile 128x32
        int c = tid + 256 * i; int n = c >> 2, cc = (c & 3) * 8;
        short8 wv = *(const short8*)(W1b + ((size_t)(nh * 128 + n)) * K1P + kk + cc);
        *(short8*)&wtile[n * 40 + cc] = wv;
      }
      __syncthreads();
      short8 af[4], bfr[4];
#pragma unroll
      for (int a = 0; a < 4; ++a) af[a]  = *(const short8*)&atile[(wm * 64 + a * 16 + l15) * 40 + lq * 8];
#pragma unroll
      for (int t = 0; t < 4; ++t) bfr[t] = *(const short8*)&wtile[(wn * 64 + t * 16 + l15) * 40 + lq * 8];
#pragma unroll
      for (int a = 0; a < 4; ++a)
#pragma unroll
        for (int t = 0; t < 4; ++t)
          acc[a][t] = __builtin_amdgcn_mfma_f32_16x16x32_bf16(af[a], bfr[t], acc[a][t], 0, 0, 0);
      __syncthreads();
    }
#pragma unroll
    for (int t = 0; t < 4; ++t) {
      int col = nh * 128 + wn * 64 + t * 16 + l15;
      float bv = b1[col];
#pragma unroll
      for (int a = 0; a < 4; ++a)
#pragma unroll
        for (int r4 = 0; r4 < 4; ++r4) {
          int row = wm * 64 + a * 16 + lq * 4 + r4;
          act1[row * 264 + col] = f2bf(fmaxf(acc[a][t][r4] + bv, 0.f));
        }
    }
  }
  __syncthreads();

  layer_234<0>(act1, act2, W2b, b2, nullptr, band, wtile, tid, wm, wn, l15, lq);
  layer_234<1>(act2, act1, W3b, b3, nullptr, band, wtile, tid, wm, wn, l15, lq);
  layer_234<2>(act1, nullptr, Wlb, nullptr, out, band, wtile, tid, wm, wn, l15, lq);
}

// ---------------------------------------------------------------- host schedule
static void build_sched(SchedArgs& P, CombArgs& CB, ChainArgs& CH, FuseArgs& FU) {
  double tb[SLEN], tt[WIN], tu[NWIN];
  const double s999 = 1.0 / (double)(SLEN - 1);
  const double s63  = 1.0 / (double)(WIN - 1);
  for (int i = 0; i < SLEN; ++i) tb[i] = (double)i * s999;
  tb[SLEN - 1] = 1.0;
  for (int k = 0; k < WIN; ++k) tt[k] = (double)k * s63;
  tt[WIN - 1] = 1.0;
  for (int j = 0; j < NWIN; ++j) tu[j] = tb[50 * j];

  int t_idx[WIN - 1], u_for_t[WIN - 1];
  for (int k = 1; k < WIN; ++k) {
    int ii = 0;
    for (int q = 0; q < SLEN; ++q) if (tb[q] <= tt[k]) ii = q;
    t_idx[k - 1] = ii;
    int jj = 0;
    for (int q = 0; q < NWIN; ++q) if (tu[q] <= tt[k]) jj = q;
    u_for_t[k - 1] = jj;
  }
  for (int t = 0; t < SLEN - 1; ++t) P.snapk[t] = 0;
  for (int m = 1; m < WIN; ++m) P.snapk[t_idx[m - 1] - 1] = (short)m;

  for (int m = 0; m < WIN; ++m) { CB.winofm[m] = 0; CB.zl[m] = 0; }
  for (int m = 1; m < WIN; ++m) {
    int p = t_idx[m - 1];
    CB.winofm[m] = (unsigned char)((p - 1) / 50);
    CB.zl[m] = (p % 50 == 0) ? 1 : 0;
  }

  double qt[32]; int nq = 0, last = -1;
  for (int m = 0; m < WIN - 1; ++m) {
    const int iu = u_for_t[m];
    if (iu != last) { qt[nq++] = tu[iu]; last = iu; }
  }
  qt[nq++] = tt[WIN - 1];
  int upd[WIN]; int qh = 0;
  for (int i = 0; i < WIN; ++i) {
    upd[i] = 0;
    if (qh < nq && tt[i] >= qt[qh]) { qh++; upd[i] = 1; }
  }
  int nU = 0;
  for (int k = 0; k < WIN; ++k) if (upd[k]) { if (nU < 32) CH.kU[nU] = (unsigned char)k; ++nU; }
  int cnt = 0;
  for (int k = 0; k < WIN; ++k) { FU.sidx[k] = (unsigned char)cnt; if (upd[k]) ++cnt; }
  CH.nsteps = FU.sidx[WIN - 1];
}

extern "C" void kernel_launch(void* const* d_in, const int* in_sizes, int n_in,
                              void* d_out, int out_size, void* d_ws, size_t ws_size,
                              hipStream_t stream) {
  const float* z  = (const float*)d_in[0];
  const float* W1 = (const float*)d_in[1];
  const float* b1 = (const float*)d_in[2];
  const float* W2 = (const float*)d_in[3];
  const float* b2 = (const float*)d_in[4];
  const float* W3 = (const float*)d_in[5];
  const float* b3 = (const float*)d_in[6];
  const float* Wl = (const float*)d_in[7];

  char* ws = (char*)d_ws;
  float* logsig = (float*)(ws);                                         // 17.83 MB
  size_t o = (size_t)B_SZ * WIN * LSIG * 4;
  float* dxwin            = (float*)(ws + o); o += (size_t)B_SZ * NWIN * DD * 4;
  unsigned short* statesb = (unsigned short*)(ws + o); o += (size_t)B_SZ * MAXST * HID * 2;
  unsigned short* W1b     = (unsigned short*)(ws + o); o += (size_t)HID * K1P * 2;
  unsigned short* W2b     = (unsigned short*)(ws + o); o += (size_t)HID * HID * 2;
  unsigned short* W3b     = (unsigned short*)(ws + o); o += (size_t)HID * HID * 2;
  unsigned short* Wlb     = (unsigned short*)(ws + o); o += (size_t)HID * HID * 2;
  unsigned short* W1f     = (unsigned short*)(ws + o); o += (size_t)13 * 16 * 64 * 8 * 2;
  unsigned short* W2f     = (unsigned short*)(ws + o); o += (size_t)8 * 16 * 64 * 8 * 2;
  unsigned short* W3f     = (unsigned short*)(ws + o); o += (size_t)8 * 16 * 64 * 8 * 2;

  SchedArgs P; CombArgs CB; ChainArgs CH; FuseArgs FU;
  build_sched(P, CB, CH, FU);

  const int wbf_total = HID * K1P + 3 * HID * HID + 13 * 16 * 64 * 8 + 2 * 8 * 16 * 64 * 8;
  wbf_kernel<<<(wbf_total + 255) / 256, 256, 0, stream>>>(
      W1, W2, W3, Wl, W1b, W2b, W3b, Wlb, W1f, W2f, W3f);
  win_kernel<<<dim3(NWIN, B_SZ), 128, 0, stream>>>(z, logsig, dxwin, P);
  comb_kernel<<<B_SZ, 128, 0, stream>>>(logsig, dxwin, CB);
  chain_kernel<<<32, 512, 0, stream>>>(logsig, W1f, W2f, W3f, b1, b2, b3, statesb, CH);
  fused_kernel<<<256, 256, 0, stream>>>(statesb, logsig, W1b, W2b, W3b, Wlb,
                                        b1, b2, b3, (float*)d_out, FU);
}